// Round 7
// baseline (384.445 us; speedup 1.0000x reference)
//
#include <hip/hip_runtime.h>
#include <hip/hip_bf16.h>

// Problem constants
#define NB    8
#define SQN   2048
#define SKN   4096
#define DDIM  512
#define DVDIM 256
#define NROWS (NB*SQN)      // 16384
#define NS    2             // SK splits
#define NJ    ((SKN/64)/NS) // 32 j-iterations per split
#define NBLK  (256*NS)      // 512 blocks, exactly 2/CU (residency-guaranteed)

typedef __attribute__((ext_vector_type(8))) short bf16x8;   // 8 bf16 = 4 VGPRs (MFMA A/B frag)
typedef __attribute__((ext_vector_type(4))) short bf16x4;
typedef __attribute__((ext_vector_type(4))) float f32x4;    // MFMA C/D frag

// fp32 -> bf16 round-to-nearest-even
__device__ __forceinline__ short f2bf(float f) {
    unsigned u = __float_as_uint(f);
    return (short)((u + 0x7FFFu + ((u >> 16) & 1u)) >> 16);
}

// async global->LDS, 16B/lane; LDS dst = wave-uniform base + lane*16,
// global src may be per-lane (read-side swizzle)
__device__ __forceinline__ void gload_lds16(const void* g, void* l) {
    __builtin_amdgcn_global_load_lds(
        (const __attribute__((address_space(1))) unsigned int*)g,
        (__attribute__((address_space(3))) unsigned int*)l, 16, 0, 0);
}

// ---------------------------------------------------------------------------
// Single persistent kernel: projections -> global barrier -> flash attention
// (R2-proven 8-barrier body) -> per-qblock rendezvous combine. ONE launch
// (R6 post-mortem: each extra launch costs ~30 us wall).
// grid = (256, NS), block = 256 (4 waves x 16 Q-rows). LDS 56 KB -> 2 blk/CU;
// VGPR ~130 << 256 -> all 512 blocks co-resident -> spin barrier is safe.
// launch_bounds(256,2) ONLY (R4 lesson: forcing 3 => scratch spill, 2x HBM).
// ---------------------------------------------------------------------------
__global__ __launch_bounds__(256, 2) void attn_all(
    const float* __restrict__ X,    // [16384][512]
    const float* __restrict__ Y,    // [4096][512]
    const float* __restrict__ Z,    // [4096][512]
    const float* __restrict__ Wk,   // [512][512]
    const float* __restrict__ Wv,   // [256][512]
    unsigned short* __restrict__ keyb,  // ws: key bf16 [4096][512]
    unsigned short* __restrict__ vtb,   // ws: V^T bf16 [256][4096]
    float* __restrict__ Opart,          // ws: [NS][16384][256]
    float* __restrict__ Mpart,          // ws: [NS][16384]
    float* __restrict__ Lpart,          // ws: [NS][16384]
    int* __restrict__ sync,             // ws: [0]=barrier, [1+qb]=order, [257+qb]=ready
    float* __restrict__ out)
{
    __shared__ char smem[57344];                 // 56 KB, phase-aliased
    short* sK = (short*)smem;                    // attn: 16 KB K chunk (swizzled)
    short* sV = (short*)(smem + 16384);          // attn: 32 KB V^T tile (swizzled)
    short* sP = (short*)(smem + 49152);          // attn:  8 KB P (wave-private)
    short* sA = (short*)smem;                    // proj: 16 KB
    short* sB = (short*)(smem + 16384);          // proj: 16 KB

    const int tid  = threadIdx.x;
    const int wave = tid >> 6;
    const int lane = tid & 63;
    const int quad = lane >> 4;
    const int l15  = lane & 15;
    const int l7   = lane & 7;
    const int qb    = blockIdx.x;
    const int split = blockIdx.y;
    const int bid   = split * 256 + qb;
    const int q0    = qb * 64;
    const float scale = 0.04419417382415922f;    // 1/sqrt(512)

    // ================= phase 1: projection GEMM tiles =================
    // 768 NT 64x64 tiles over 512 blocks (t<512: key = Y*Wk^T; else vt = Wv*Z^T)
    for (int t = bid; t < 768; t += NBLK) {
        const float *A, *Bm;
        unsigned short* C;
        int N, m0, n0;
        if (t < 512) { A = Y;  Bm = Wk; C = keyb; N = DDIM; m0 = (t >> 3) << 6; n0 = (t & 7) << 6; }
        else { int tt = t - 512; A = Wv; Bm = Z; C = vtb; N = SKN; m0 = (tt >> 6) << 6; n0 = (tt & 63) << 6; }

        f32x4 acc[4];
        #pragma unroll
        for (int n = 0; n < 4; ++n) { acc[n][0]=0.f; acc[n][1]=0.f; acc[n][2]=0.f; acc[n][3]=0.f; }
        float4 ra[8], rb[8];
        #pragma unroll
        for (int it = 0; it < 8; ++it) {         // prefetch kc=0
            int f = it*1024 + tid*4, row = f >> 7, col = f & 127;
            ra[it] = *(const float4*)(A  + (size_t)(m0+row)*DDIM + col);
            rb[it] = *(const float4*)(Bm + (size_t)(n0+row)*DDIM + col);
        }
        for (int kc = 0; kc < DDIM; kc += 128) {
            __syncthreads();
            #pragma unroll
            for (int it = 0; it < 8; ++it) {
                int f = it*1024 + tid*4;
                bf16x4 a4; a4[0]=f2bf(ra[it].x); a4[1]=f2bf(ra[it].y); a4[2]=f2bf(ra[it].z); a4[3]=f2bf(ra[it].w);
                *(bf16x4*)(sA + f) = a4;
                bf16x4 b4; b4[0]=f2bf(rb[it].x); b4[1]=f2bf(rb[it].y); b4[2]=f2bf(rb[it].z); b4[3]=f2bf(rb[it].w);
                *(bf16x4*)(sB + f) = b4;
            }
            __syncthreads();
            if (kc + 128 < DDIM) {
                #pragma unroll
                for (int it = 0; it < 8; ++it) {
                    int f = it*1024 + tid*4, row = f >> 7, col = f & 127;
                    ra[it] = *(const float4*)(A  + (size_t)(m0+row)*DDIM + kc + 128 + col);
                    rb[it] = *(const float4*)(Bm + (size_t)(n0+row)*DDIM + kc + 128 + col);
                }
            }
            #pragma unroll
            for (int tt2 = 0; tt2 < 4; ++tt2) {
                bf16x8 af = *(const bf16x8*)(sA + (wave*16 + l15)*128 + tt2*32 + quad*8);
                #pragma unroll
                for (int n = 0; n < 4; ++n) {
                    bf16x8 bfr = *(const bf16x8*)(sB + (n*16 + l15)*128 + tt2*32 + quad*8);
                    acc[n] = __builtin_amdgcn_mfma_f32_16x16x32_bf16(af, bfr, acc[n], 0, 0, 0);
                }
            }
        }
        #pragma unroll
        for (int n = 0; n < 4; ++n)
            #pragma unroll
            for (int r = 0; r < 4; ++r) {
                int m  = m0 + wave*16 + quad*4 + r;
                int nn = n0 + n*16 + l15;
                C[(size_t)m*N + nn] = (unsigned short)f2bf(acc[n][r]);
            }
    }
    __syncthreads();   // all waves' proj stores drained (vmcnt(0) before barrier)

    // Q fragments now: X-read latency overlaps the global-barrier wait below.
    bf16x8 qf[16];
    {
        const float* xrow = X + (size_t)(q0 + wave*16 + l15) * DDIM;
        #pragma unroll
        for (int t = 0; t < 16; ++t) {
            float4 a = *(const float4*)(xrow + t*32 + quad*8);
            float4 b = *(const float4*)(xrow + t*32 + quad*8 + 4);
            bf16x8 q;
            q[0]=f2bf(a.x*scale); q[1]=f2bf(a.y*scale); q[2]=f2bf(a.z*scale); q[3]=f2bf(a.w*scale);
            q[4]=f2bf(b.x*scale); q[5]=f2bf(b.y*scale); q[6]=f2bf(b.z*scale); q[7]=f2bf(b.w*scale);
            qf[t] = q;
        }
    }

    // ================= global barrier (all 512 blocks co-resident) =========
    // Writer: __threadfence (L2 writeback) before add. Reader: each block's
    // acquire-load invalidates its own XCD L2 (G16 cross-XCD safety).
    if (tid == 0) {
        __threadfence();
        __hip_atomic_fetch_add(&sync[0], 1, __ATOMIC_ACQ_REL, __HIP_MEMORY_SCOPE_AGENT);
        while (__hip_atomic_load(&sync[0], __ATOMIC_ACQUIRE, __HIP_MEMORY_SCOPE_AGENT) < NBLK)
            __builtin_amdgcn_s_sleep(10);
    }
    __syncthreads();

    // ================= phase 2: flash attention (R2 body) ==================
    f32x4 o[16];
    #pragma unroll
    for (int i = 0; i < 16; ++i) { o[i][0]=0.f; o[i][1]=0.f; o[i][2]=0.f; o[i][3]=0.f; }
    float m_r[4] = {-1e30f,-1e30f,-1e30f,-1e30f};
    float l_r[4] = {0.f,0.f,0.f,0.f};
    short* sPw = sP + wave*1024;             // 16 rows x 64 keys, wave-private

    const int wq   = wave*4 + quad;          // K-stage dest row phase (= row & 15)
    const int vrow = wave*8 + (lane>>3);     // V-stage dest dv phase
    const int vswz = (l7 ^ (lane>>3)) << 3;
    const int sb0  = split * NJ;

    for (int j = 0; j < NJ; ++j) {
        const int sk0 = (sb0 + j) * 64;
        f32x4 s[4];
        #pragma unroll
        for (int n = 0; n < 4; ++n) { s[n][0]=0.f; s[n][1]=0.f; s[n][2]=0.f; s[n][3]=0.f; }

        #pragma unroll
        for (int c = 0; c < 4; ++c) {
            __syncthreads();   // (A) prior consumers of sK (and sV at c==0) done
            if (c == 0) {
                // stage whole V^T tile 256x64 (swizzled src, linear dst)
                const unsigned short* vsrc = vtb + sk0 + (size_t)vrow*SKN + vswz;
                char* vdst = (char*)sV + wave*1024;
                #pragma unroll
                for (int it = 0; it < 8; ++it)
                    gload_lds16(vsrc + (size_t)it*32*SKN, vdst + it*4096);
            }
            // stage K chunk 64x128 (swizzled src, linear dst)
            const unsigned short* ksrc = keyb + (size_t)(sk0 + wq)*DDIM
                + c*128 + ((l15 ^ wq) << 3);
            char* kdst = (char*)sK + wave*1024;
            #pragma unroll
            for (int it = 0; it < 4; ++it)
                gload_lds16(ksrc + (size_t)it*16*DDIM, kdst + it*4096);
            __syncthreads();   // (B) staged data visible
            // S += Q_chunk * K_chunk^T
            #pragma unroll
            for (int t = 0; t < 4; ++t) {
                bf16x8 af = qf[c*4 + t];
                #pragma unroll
                for (int n = 0; n < 4; ++n) {
                    bf16x8 bfr = *(const bf16x8*)(sK + (n*16 + l15)*128
                                                  + (((t*4 + quad) ^ l15) << 3));
                    s[n] = __builtin_amdgcn_mfma_f32_16x16x32_bf16(af, bfr, s[n], 0, 0, 0);
                }
            }
        }

        // ---- online softmax (rows = quad*4+r), P written inline to sP ----
        float alpha[4];
        int need_rescale = 0;
        #pragma unroll
        for (int r = 0; r < 4; ++r) {
            float v = fmaxf(fmaxf(s[0][r], s[1][r]), fmaxf(s[2][r], s[3][r]));
            v = fmaxf(v, __shfl_xor(v, 1));
            v = fmaxf(v, __shfl_xor(v, 2));
            v = fmaxf(v, __shfl_xor(v, 4));
            v = fmaxf(v, __shfl_xor(v, 8));
            float mn = fmaxf(m_r[r], v);
            float a  = __expf(m_r[r] - mn);
            alpha[r] = a;
            need_rescale |= (a < 1.0f);
            m_r[r] = mn;
            const int row = quad*4 + r;
            short* prow = sPw + row*64 + l7;
            const int rx = row & 7;
            float sum = 0.f;
            #pragma unroll
            for (int n = 0; n < 4; ++n) {
                float pv = __expf(s[n][r] - mn);
                sum += pv;
                prow[((n*2 + (l15 >> 3)) ^ rx) << 3] = f2bf(pv);
            }
            sum += __shfl_xor(sum, 1);
            sum += __shfl_xor(sum, 2);
            sum += __shfl_xor(sum, 4);
            sum += __shfl_xor(sum, 8);
            l_r[r] = l_r[r]*a + sum;
        }
        if (__any(need_rescale)) {
            #pragma unroll
            for (int n2 = 0; n2 < 16; ++n2)
                #pragma unroll
                for (int r = 0; r < 4; ++r) o[n2][r] *= alpha[r];
        }

        // ---- PV: O += P * V^T (same-wave P; no barrier) ----
        #pragma unroll
        for (int t2 = 0; t2 < 2; ++t2) {
            const int cx = (((t2*4 + quad) ^ l7) << 3);
            bf16x8 af = *(const bf16x8*)(sPw + l15*64 + cx);
            #pragma unroll
            for (int n2 = 0; n2 < 16; ++n2) {
                bf16x8 bfr = *(const bf16x8*)(sV + (n2*16 + l15)*64 + cx);
                o[n2] = __builtin_amdgcn_mfma_f32_16x16x32_bf16(af, bfr, o[n2], 0, 0, 0);
            }
        }
    }

    // ================= phase 3: rendezvous combine =================
    __syncthreads();                       // sP reads done; smem reusable
    int* s_flag = (int*)smem;
    if (tid == 0)
        s_flag[0] = __hip_atomic_fetch_add(&sync[1 + qb], 1, __ATOMIC_ACQ_REL,
                                           __HIP_MEMORY_SCOPE_AGENT);
    __syncthreads();
    const int ticket = s_flag[0];

    if (ticket == 0) {
        // first arriver: publish partials, release ready-flag, exit
        #pragma unroll
        for (int r = 0; r < 4; ++r) {
            int row = q0 + wave*16 + quad*4 + r;
            if (l15 == 0) {
                Mpart[(size_t)split*NROWS + row] = m_r[r];
                Lpart[(size_t)split*NROWS + row] = l_r[r];
            }
            float* orow = Opart + ((size_t)split*NROWS + row) * DVDIM;
            #pragma unroll
            for (int n2 = 0; n2 < 16; ++n2)
                orow[n2*16 + l15] = o[n2][r];
        }
        __syncthreads();                   // all waves' stores drained
        if (tid == 0) {
            __threadfence();               // L2 writeback before release
            __hip_atomic_store(&sync[257 + qb], 1, __ATOMIC_RELEASE,
                               __HIP_MEMORY_SCOPE_AGENT);
        }
    } else {
        // second arriver: combine own registers with partner's memory partials
        if (tid == 0) {
            while (!__hip_atomic_load(&sync[257 + qb], __ATOMIC_ACQUIRE,
                                      __HIP_MEMORY_SCOPE_AGENT))
                __builtin_amdgcn_s_sleep(4);
        }
        __syncthreads();
        const int os = 1 - split;
        #pragma unroll
        for (int r = 0; r < 4; ++r) {
            int row = q0 + wave*16 + quad*4 + r;
            float mp = Mpart[(size_t)os*NROWS + row];
            float lp = Lpart[(size_t)os*NROWS + row];
            float M  = fmaxf(m_r[r], mp);
            float w0 = __expf(m_r[r] - M), w1 = __expf(mp - M);
            float inv = 1.0f / (l_r[r]*w0 + lp*w1);
            const float* prow = Opart + ((size_t)os*NROWS + row) * DVDIM;
            float* orow = out + (size_t)row * DVDIM;
            #pragma unroll
            for (int n2 = 0; n2 < 16; ++n2)
                orow[n2*16 + l15] = (o[n2][r]*w0 + prow[n2*16 + l15]*w1) * inv;
        }
    }
}

extern "C" void kernel_launch(void* const* d_in, const int* in_sizes, int n_in,
                              void* d_out, int out_size, void* d_ws, size_t ws_size,
                              hipStream_t stream) {
    const float* X  = (const float*)d_in[0];
    const float* Y  = (const float*)d_in[1];
    const float* Z  = (const float*)d_in[2];
    const float* Wk = (const float*)d_in[3];
    const float* Wv = (const float*)d_in[4];
    float* out = (float*)d_out;

    // workspace layout (~38.26 MB)
    char* ws = (char*)d_ws;
    unsigned short* keyb = (unsigned short*)ws;                     // 4 MB
    unsigned short* vtb  = (unsigned short*)(ws + (4u<<20));        // 2 MB
    float* Opart = (float*)(ws + (6u<<20));                         // 32 MB
    float* Mpart = (float*)(ws + (6u<<20) + (32u<<20));             // 128 KB
    float* Lpart = (float*)(ws + (6u<<20) + (32u<<20) + 131072u);   // 128 KB
    int*   sync  = (int*)  (ws + (6u<<20) + (32u<<20) + 262144u);   // 4 KB

    hipMemsetAsync(sync, 0, 4096, stream);   // ws is poisoned 0xAA before each launch
    attn_all<<<dim3(256, NS), dim3(256), 0, stream>>>(
        X, Y, Z, Wk, Wv, keyb, vtb, Opart, Mpart, Lpart, sync, out);
}

// Round 8
// 302.824 us; speedup vs baseline: 1.2695x; 1.2695x over previous
//
#include <hip/hip_runtime.h>
#include <hip/hip_bf16.h>

// Problem constants
#define NB    8
#define SQN   2048
#define SKN   4096
#define DDIM  512
#define DVDIM 256
#define NROWS (NB*SQN)      // 16384

typedef __attribute__((ext_vector_type(8))) short bf16x8;   // 8 bf16 = 4 VGPRs (MFMA A/B frag)
typedef __attribute__((ext_vector_type(4))) short bf16x4;
typedef __attribute__((ext_vector_type(4))) float f32x4;    // MFMA C/D frag

// fp32 -> bf16 round-to-nearest-even
__device__ __forceinline__ short f2bf(float f) {
    unsigned u = __float_as_uint(f);
    return (short)((u + 0x7FFFu + ((u >> 16) & 1u)) >> 16);
}

// async global->LDS, 16B/lane; LDS dst = wave-uniform base + lane*16,
// global src may be per-lane (read-side swizzle)
__device__ __forceinline__ void gload_lds16(const void* g, void* l) {
    __builtin_amdgcn_global_load_lds(
        (const __attribute__((address_space(1))) unsigned int*)g,
        (__attribute__((address_space(3))) unsigned int*)l, 16, 0, 0);
}

// ---------------------------------------------------------------------------
// Fused projection GEMMs, one launch, 1-D grid 768 (no dead blocks).
//  t < 512:  key[s][d] = sum_c Y[s][c]*Wk[d][c]   (4096x512, 64x64 tiles)
//  t >= 512: vt[dv][s] = sum_c Wv[dv][c]*Z[s][c]  (256x4096)
// NT GEMM, Kc=128, staging double-buffered through registers.
// ---------------------------------------------------------------------------
__global__ __launch_bounds__(256, 2) void proj_gemms(
    const float* __restrict__ Y, const float* __restrict__ Z,
    const float* __restrict__ Wk, const float* __restrict__ Wv,
    unsigned short* __restrict__ keyb, unsigned short* __restrict__ vtb)
{
    __shared__ short sA[64*128];   // 16 KB
    __shared__ short sB[64*128];   // 16 KB
    const int t = blockIdx.x;
    const float *A, *Bm;
    unsigned short* C;
    int N, m0, n0;
    if (t < 512) { A = Y;  Bm = Wk; C = keyb; N = DDIM; m0 = (t >> 3) << 6; n0 = (t & 7) << 6; }
    else { int tt = t - 512; A = Wv; Bm = Z; C = vtb; N = SKN; m0 = (tt >> 6) << 6; n0 = (tt & 63) << 6; }

    const int tid  = threadIdx.x;
    const int wave = tid >> 6;
    const int lane = tid & 63;
    const int quad = lane >> 4;
    const int l15  = lane & 15;

    f32x4 acc[4];
    #pragma unroll
    for (int n = 0; n < 4; ++n) { acc[n][0]=0.f; acc[n][1]=0.f; acc[n][2]=0.f; acc[n][3]=0.f; }

    float4 ra[8], rb[8];
    #pragma unroll
    for (int it = 0; it < 8; ++it) {            // prefetch kc=0
        int f = it*1024 + tid*4, row = f >> 7, col = f & 127;
        ra[it] = *(const float4*)(A  + (size_t)(m0+row)*DDIM + col);
        rb[it] = *(const float4*)(Bm + (size_t)(n0+row)*DDIM + col);
    }
    for (int kc = 0; kc < DDIM; kc += 128) {
        __syncthreads();
        #pragma unroll
        for (int it = 0; it < 8; ++it) {
            int f = it*1024 + tid*4;
            bf16x4 a4; a4[0]=f2bf(ra[it].x); a4[1]=f2bf(ra[it].y); a4[2]=f2bf(ra[it].z); a4[3]=f2bf(ra[it].w);
            *(bf16x4*)(sA + f) = a4;
            bf16x4 b4; b4[0]=f2bf(rb[it].x); b4[1]=f2bf(rb[it].y); b4[2]=f2bf(rb[it].z); b4[3]=f2bf(rb[it].w);
            *(bf16x4*)(sB + f) = b4;
        }
        __syncthreads();
        if (kc + 128 < DDIM) {                  // prefetch kc+1 under MFMA
            #pragma unroll
            for (int it = 0; it < 8; ++it) {
                int f = it*1024 + tid*4, row = f >> 7, col = f & 127;
                ra[it] = *(const float4*)(A  + (size_t)(m0+row)*DDIM + kc + 128 + col);
                rb[it] = *(const float4*)(Bm + (size_t)(n0+row)*DDIM + kc + 128 + col);
            }
        }
        #pragma unroll
        for (int tt2 = 0; tt2 < 4; ++tt2) {
            bf16x8 af = *(const bf16x8*)(sA + (wave*16 + l15)*128 + tt2*32 + quad*8);
            #pragma unroll
            for (int n = 0; n < 4; ++n) {
                bf16x8 bfr = *(const bf16x8*)(sB + (n*16 + l15)*128 + tt2*32 + quad*8);
                acc[n] = __builtin_amdgcn_mfma_f32_16x16x32_bf16(af, bfr, acc[n], 0, 0, 0);
            }
        }
    }
    #pragma unroll
    for (int n = 0; n < 4; ++n)
        #pragma unroll
        for (int r = 0; r < 4; ++r) {
            int m  = m0 + wave*16 + quad*4 + r;
            int nn = n0 + n*16 + l15;
            C[(size_t)m*N + nn] = (unsigned short)f2bf(acc[n][r]);
        }
}

// ---------------------------------------------------------------------------
// Fused attention: grid = (NROWS/64, ns), block = 256 (4 waves x 16 Q-rows).
// R2-proven body (187us measured) with sP ALIASED into sK: LDS 48 KB ->
// HW residency 3 blocks/CU (160/48) — occupancy raised via LDS shrink only,
// launch_bounds stays (256,2) (R4 lesson: forcing 3 => scratch spill).
// ns=4 splits give 1024 blocks so 3/CU can actually be used.
// Per j: 4x(barrier A; stage K_c (+whole V at c==0); barrier B; QK_c);
//        barrier C (all sK reads done -> P may overwrite alias);
//        softmax + P->sP; PV (same-wave P, no barrier). 9 barriers/j.
// ---------------------------------------------------------------------------
__global__ __launch_bounds__(256, 2) void attn_fused(
    const float* __restrict__ X,            // [16384][512] fp32
    const unsigned short* __restrict__ Kb,  // key bf16 [4096][512] natural
    const unsigned short* __restrict__ Vt,  // V^T bf16 [256][4096] natural
    float* __restrict__ Opart,              // [ns][16384][256]
    float* __restrict__ Mpart,              // [ns][16384]
    float* __restrict__ Lpart,              // [ns][16384]
    int nj)                                 // key-blocks per split
{
    __shared__ char smem[49152];    // 48 KB total
    short* sK = (short*)smem;               // 16 KB: K chunk 64x128 (swizzled)
    short* sV = (short*)(smem + 16384);     // 32 KB: V^T 256x64 (swizzled)
    short* sP = (short*)smem;               //  8 KB: alias of sK[0..8K)
    const int tid  = threadIdx.x;
    const int wave = tid >> 6;
    const int lane = tid & 63;
    const int quad = lane >> 4;
    const int l15  = lane & 15;
    const int l7   = lane & 7;
    const int split = blockIdx.y;
    const int q0   = blockIdx.x * 64;
    const int sb0  = split * nj;
    const float scale = 0.04419417382415922f;  // 1/sqrt(512)

    // Q fragments (scale folded): A[m=l15][k=quad*8+i], 16 k-steps (64 VGPRs)
    bf16x8 qf[16];
    {
        const float* xrow = X + (size_t)(q0 + wave*16 + l15) * DDIM;
        #pragma unroll
        for (int t = 0; t < 16; ++t) {
            float4 a = *(const float4*)(xrow + t*32 + quad*8);
            float4 b = *(const float4*)(xrow + t*32 + quad*8 + 4);
            bf16x8 q;
            q[0]=f2bf(a.x*scale); q[1]=f2bf(a.y*scale); q[2]=f2bf(a.z*scale); q[3]=f2bf(a.w*scale);
            q[4]=f2bf(b.x*scale); q[5]=f2bf(b.y*scale); q[6]=f2bf(b.z*scale); q[7]=f2bf(b.w*scale);
            qf[t] = q;
        }
    }

    f32x4 o[16];
    #pragma unroll
    for (int i = 0; i < 16; ++i) { o[i][0]=0.f; o[i][1]=0.f; o[i][2]=0.f; o[i][3]=0.f; }
    float m_r[4] = {-1e30f,-1e30f,-1e30f,-1e30f};
    float l_r[4] = {0.f,0.f,0.f,0.f};
    short* sPw = sP + wave*1024;             // 16 rows x 64 keys, wave-private

    // read-side swizzle constants (measured conflict-free, R5/R6: 0 conflicts)
    const int wq   = wave*4 + quad;          // K-stage dest row phase (= row & 15)
    const int vrow = wave*8 + (lane>>3);     // V-stage dest dv phase
    const int vswz = (l7 ^ (lane>>3)) << 3;

    for (int j = 0; j < nj; ++j) {
        const int sk0 = (sb0 + j) * 64;
        f32x4 s[4];
        #pragma unroll
        for (int n = 0; n < 4; ++n) { s[n][0]=0.f; s[n][1]=0.f; s[n][2]=0.f; s[n][3]=0.f; }

        #pragma unroll
        for (int c = 0; c < 4; ++c) {
            __syncthreads();   // (A) prior consumers of sK/sP (and sV at c==0) done
            if (c == 0) {
                // stage whole V^T tile 256x64 (swizzled src, linear dst)
                const unsigned short* vsrc = Vt + sk0 + (size_t)vrow*SKN + vswz;
                char* vdst = (char*)sV + wave*1024;
                #pragma unroll
                for (int it = 0; it < 8; ++it)
                    gload_lds16(vsrc + (size_t)it*32*SKN, vdst + it*4096);
            }
            // stage K chunk 64x128 (swizzled src, linear dst)
            const unsigned short* ksrc = Kb + (size_t)(sk0 + wq)*DDIM
                + c*128 + ((l15 ^ wq) << 3);
            char* kdst = (char*)sK + wave*1024;
            #pragma unroll
            for (int it = 0; it < 4; ++it)
                gload_lds16(ksrc + (size_t)it*16*DDIM, kdst + it*4096);
            __syncthreads();   // (B) staged data visible
            // S += Q_chunk * K_chunk^T
            #pragma unroll
            for (int t = 0; t < 4; ++t) {
                bf16x8 af = qf[c*4 + t];
                #pragma unroll
                for (int n = 0; n < 4; ++n) {
                    bf16x8 bfr = *(const bf16x8*)(sK + (n*16 + l15)*128
                                                  + (((t*4 + quad) ^ l15) << 3));
                    s[n] = __builtin_amdgcn_mfma_f32_16x16x32_bf16(af, bfr, s[n], 0, 0, 0);
                }
            }
        }
        __syncthreads();       // (C) all QK reads of sK done -> P may overwrite alias

        // ---- online softmax (rows = quad*4+r), P written inline to sP ----
        float alpha[4];
        int need_rescale = 0;
        #pragma unroll
        for (int r = 0; r < 4; ++r) {
            float v = fmaxf(fmaxf(s[0][r], s[1][r]), fmaxf(s[2][r], s[3][r]));
            v = fmaxf(v, __shfl_xor(v, 1));
            v = fmaxf(v, __shfl_xor(v, 2));
            v = fmaxf(v, __shfl_xor(v, 4));
            v = fmaxf(v, __shfl_xor(v, 8));
            float mn = fmaxf(m_r[r], v);
            float a  = __expf(m_r[r] - mn);
            alpha[r] = a;
            need_rescale |= (a < 1.0f);
            m_r[r] = mn;
            const int row = quad*4 + r;
            short* prow = sPw + row*64 + l7;
            const int rx = row & 7;
            float sum = 0.f;
            #pragma unroll
            for (int n = 0; n < 4; ++n) {
                float pv = __expf(s[n][r] - mn);
                sum += pv;
                prow[((n*2 + (l15 >> 3)) ^ rx) << 3] = f2bf(pv);
            }
            sum += __shfl_xor(sum, 1);
            sum += __shfl_xor(sum, 2);
            sum += __shfl_xor(sum, 4);
            sum += __shfl_xor(sum, 8);
            l_r[r] = l_r[r]*a + sum;
        }
        if (__any(need_rescale)) {
            #pragma unroll
            for (int n2 = 0; n2 < 16; ++n2)
                #pragma unroll
                for (int r = 0; r < 4; ++r) o[n2][r] *= alpha[r];
        }

        // ---- PV: O += P * V^T (same-wave P; no barrier) ----
        #pragma unroll
        for (int t2 = 0; t2 < 2; ++t2) {
            const int cx = (((t2*4 + quad) ^ l7) << 3);
            bf16x8 af = *(const bf16x8*)(sPw + l15*64 + cx);
            #pragma unroll
            for (int n2 = 0; n2 < 16; ++n2) {
                bf16x8 bfr = *(const bf16x8*)(sV + (n2*16 + l15)*64 + cx);
                o[n2] = __builtin_amdgcn_mfma_f32_16x16x32_bf16(af, bfr, o[n2], 0, 0, 0);
            }
        }
    }

    // epilogue: unnormalized O + (m,l) per row
    const size_t base = (size_t)split * NROWS;
    #pragma unroll
    for (int r = 0; r < 4; ++r) {
        int row = q0 + wave*16 + quad*4 + r;
        if (l15 == 0) { Mpart[base + row] = m_r[r]; Lpart[base + row] = l_r[r]; }
        float* orow = Opart + (base + row) * (size_t)DVDIM;
        #pragma unroll
        for (int n2 = 0; n2 < 16; ++n2)
            orow[n2*16 + l15] = o[n2][r];
    }
}

// ---------------------------------------------------------------------------
// Combine ns split partials: out = sum_s(Os*ws) / sum_s(ls*ws), ws=exp(ms-M).
// grid = NROWS/4, block = 256: 4 rows/block, one float4 per thread. Coalesced.
// ---------------------------------------------------------------------------
__global__ void combine_splits(
    const float* __restrict__ Opart, const float* __restrict__ Mpart,
    const float* __restrict__ Lpart, float* __restrict__ out, int ns)
{
    const int row = blockIdx.x * 4 + (threadIdx.x >> 6);
    const int dv4 = (threadIdx.x & 63) * 4;
    float M = -1e30f;
    for (int s = 0; s < ns; ++s) M = fmaxf(M, Mpart[(size_t)s*NROWS + row]);
    float denom = 0.f;
    float4 acc = make_float4(0.f, 0.f, 0.f, 0.f);
    for (int s = 0; s < ns; ++s) {
        float w = __expf(Mpart[(size_t)s*NROWS + row] - M);
        denom += Lpart[(size_t)s*NROWS + row] * w;
        float4 ov = *(const float4*)(Opart + ((size_t)s*NROWS + row)*DVDIM + dv4);
        acc.x += ov.x*w; acc.y += ov.y*w; acc.z += ov.z*w; acc.w += ov.w*w;
    }
    float inv = 1.0f / denom;
    *(float4*)(out + (size_t)row*DVDIM + dv4)
        = make_float4(acc.x*inv, acc.y*inv, acc.z*inv, acc.w*inv);
}

extern "C" void kernel_launch(void* const* d_in, const int* in_sizes, int n_in,
                              void* d_out, int out_size, void* d_ws, size_t ws_size,
                              hipStream_t stream) {
    const float* X  = (const float*)d_in[0];   // [8,2048,512]
    const float* Y  = (const float*)d_in[1];   // [4096,512]
    const float* Z  = (const float*)d_in[2];   // [4096,512]
    const float* Wk = (const float*)d_in[3];   // [512,512]
    const float* Wv = (const float*)d_in[4];   // [256,512]
    float* out = (float*)d_out;

    // choose split count by workspace budget (needs 6MB + ns*(16MB+128KB))
    size_t need4 = (size_t)(6u<<20) + 4u*((16u<<20) + (size_t)NROWS*8);
    int ns = (ws_size >= need4) ? 4 : 2;
    int nj = (SKN/64) / ns;

    char* ws = (char*)d_ws;
    unsigned short* keyb = (unsigned short*)ws;                    // 4 MB, natural [4096][512]
    unsigned short* vtb  = (unsigned short*)(ws + (4u<<20));       // 2 MB, natural [256][4096]
    float* Opart = (float*)(ws + (6u<<20));                        // ns x 16 MB
    float* Mpart = (float*)(ws + (6u<<20) + (size_t)ns*NROWS*DVDIM*4);
    float* Lpart = Mpart + (size_t)ns*NROWS;

    // both projections, one launch, 768 tiles
    proj_gemms<<<dim3(768), dim3(256), 0, stream>>>(Y, Z, Wk, Wv, keyb, vtb);
    // fused attention over ns SK-splits (1024 blocks when ns=4 -> can fill 3/CU)
    attn_fused<<<dim3(NROWS/64, ns), dim3(256), 0, stream>>>(
        X, keyb, vtb, Opart, Mpart, Lpart, nj);
    // merge splits
    combine_splits<<<dim3(NROWS/4), dim3(256), 0, stream>>>(Opart, Mpart, Lpart, out, ns);
}